// Round 1
// baseline (467.991 us; speedup 1.0000x reference)
//
#include <hip/hip_runtime.h>
#include <hip/hip_bf16.h>
#include <math.h>
#include <stdint.h>

#define BB 32
#define CC 256
#define SS 1024
// TEMP = 0.1 -> multiply by 10

// ---------------------------------------------------------------------------
// Kernel 1: inverse L2 norms along C for all four tensors.
// inv layout: [4][B*S]  (0=q_b, 1=k_b, 2=q_grid, 3=k_grid)
// ---------------------------------------------------------------------------
__global__ __launch_bounds__(256) void norms_kernel(
    const float* __restrict__ qb, const float* __restrict__ kb,
    const float* __restrict__ qg, const float* __restrict__ kg,
    float* __restrict__ inv) {
  int t = blockIdx.x * 256 + threadIdx.x;      // 0 .. 4*B*S-1
  int which = t >> 15;                          // B*S = 32768 = 2^15
  int bs = t & (BB * SS - 1);
  const float* src = (which == 0) ? qb : (which == 1) ? kb : (which == 2) ? qg : kg;
  int b = bs >> 10;
  int s = bs & (SS - 1);
  const float* p = src + (size_t)b * CC * SS + s;
  float ss = 0.f;
#pragma unroll 8
  for (int c = 0; c < CC; ++c) {
    float x = p[(size_t)c * SS];
    ss = fmaf(x, x, ss);
  }
  float n = fmaxf(sqrtf(ss), 1e-12f);
  inv[t] = 1.0f / n;
}

// ---------------------------------------------------------------------------
// Kernel 2: per-batch sim = (qb_n)^T (kb_n), row argmax over j (first-occurrence).
// Tile: TI=64 rows x TJ=128 cols, KC=32 k-chunk, 256 threads, 4x8 microtile.
// grid = B * (S/TI) = 512 blocks.
// ---------------------------------------------------------------------------
#define TI 64
#define TJ 128
#define KC 32

__global__ __launch_bounds__(256) void simargmax_kernel(
    const float* __restrict__ qb, const float* __restrict__ kb,
    const float* __restrict__ invq, const float* __restrict__ invk,
    int* __restrict__ amax) {
  const int b = blockIdx.x >> 4;               // S/TI = 16 tiles per batch
  const int i0 = (blockIdx.x & 15) * TI;
  const int t = threadIdx.x;
  const int ti = t >> 4;                        // 0..15 -> rows ti*4..+3
  const int tj = t & 15;                        // 0..15 -> cols tj*8..+7

  __shared__ float aQ[KC][TI];
  __shared__ float bK[KC][TJ];
  __shared__ float redv[TI][16];
  __shared__ int   redj[TI][16];

  const float* qbase = qb + (size_t)b * CC * SS + i0;
  const float* kbase = kb + (size_t)b * CC * SS;
  const float* ivq = invq + b * SS + i0;
  const float* ivk = invk + b * SS;

  float best_v = -3.4e38f;
  int best_j = 0;

  for (int j0 = 0; j0 < SS; j0 += TJ) {
    float acc[4][8];
#pragma unroll
    for (int r = 0; r < 4; ++r)
#pragma unroll
      for (int rr = 0; rr < 8; ++rr) acc[r][rr] = 0.f;

    for (int c0 = 0; c0 < CC; c0 += KC) {
      __syncthreads();
      // stage aQ: KC*TI = 2048 floats, 8/thread (2x float4), coalesced
#pragma unroll
      for (int v = 0; v < 2; ++v) {
        int f = t + v * 256;
        int cl = f >> 4;
        int sl = (f & 15) << 2;
        float4 qa = *(const float4*)(qbase + (size_t)(c0 + cl) * SS + sl);
        float4 iv = *(const float4*)(ivq + sl);
        aQ[cl][sl + 0] = qa.x * iv.x;
        aQ[cl][sl + 1] = qa.y * iv.y;
        aQ[cl][sl + 2] = qa.z * iv.z;
        aQ[cl][sl + 3] = qa.w * iv.w;
      }
      // stage bK: KC*TJ = 4096 floats, 16/thread (4x float4), coalesced
#pragma unroll
      for (int v = 0; v < 4; ++v) {
        int f = t + v * 256;
        int cl = f >> 5;
        int sl = (f & 31) << 2;
        float4 ka = *(const float4*)(kbase + (size_t)(c0 + cl) * SS + j0 + sl);
        float4 ik = *(const float4*)(ivk + j0 + sl);
        bK[cl][sl + 0] = ka.x * ik.x;
        bK[cl][sl + 1] = ka.y * ik.y;
        bK[cl][sl + 2] = ka.z * ik.z;
        bK[cl][sl + 3] = ka.w * ik.w;
      }
      __syncthreads();
#pragma unroll
      for (int kc = 0; kc < KC; ++kc) {
        float4 a0 = *(const float4*)&aQ[kc][ti * 4];
        float4 b0 = *(const float4*)&bK[kc][tj * 8];
        float4 b1 = *(const float4*)&bK[kc][tj * 8 + 4];
        float av[4] = {a0.x, a0.y, a0.z, a0.w};
        float bv[8] = {b0.x, b0.y, b0.z, b0.w, b1.x, b1.y, b1.z, b1.w};
#pragma unroll
        for (int r = 0; r < 4; ++r)
#pragma unroll
          for (int rr = 0; rr < 8; ++rr)
            acc[r][rr] = fmaf(av[r], bv[rr], acc[r][rr]);
      }
    }
    // per-thread argmax over its 8 cols (ascending rr + strict '>' keeps lowest j)
    __syncthreads();
#pragma unroll
    for (int r = 0; r < 4; ++r) {
      float v = acc[r][0];
      int jb = j0 + tj * 8;
#pragma unroll
      for (int rr = 1; rr < 8; ++rr) {
        if (acc[r][rr] > v) { v = acc[r][rr]; jb = j0 + tj * 8 + rr; }
      }
      redv[ti * 4 + r][tj] = v;
      redj[ti * 4 + r][tj] = jb;
    }
    __syncthreads();
    if (t < TI) {
      // ascending tj => ascending j ranges; strict '>' keeps first occurrence
#pragma unroll
      for (int w = 0; w < 16; ++w) {
        float v = redv[t][w];
        if (v > best_v) { best_v = v; best_j = redj[t][w]; }
      }
    }
  }
  if (t < TI) amax[b * SS + i0 + t] = best_j;
}

// ---------------------------------------------------------------------------
// Kernel 3: Threefry-2x32-20 (JAX key(42), iota(1024)) -> u[32][32];
// neg_idx[b] = argmax_j( labels[b]!=labels[j] ? u[b][j] : -1 )
// ---------------------------------------------------------------------------
__device__ __forceinline__ void tf_round(uint32_t& x0, uint32_t& x1, int r) {
  x0 += x1;
  x1 = (x1 << r) | (x1 >> (32 - r));
  x1 ^= x0;
}

__global__ void negidx_kernel(const int* __restrict__ labels, int* __restrict__ negidx) {
  __shared__ float u[1024];
  int t = threadIdx.x;  // 512 threads, pair (t, t+512)
  uint32_t x0 = (uint32_t)t;
  uint32_t x1 = (uint32_t)(t + 512);
  const uint32_t ks0 = 0u, ks1 = 42u, ks2 = 0x1BD11BDAu ^ 0u ^ 42u;
  x0 += ks0; x1 += ks1;
  tf_round(x0, x1, 13); tf_round(x0, x1, 15); tf_round(x0, x1, 26); tf_round(x0, x1, 6);
  x0 += ks1; x1 += ks2 + 1u;
  tf_round(x0, x1, 17); tf_round(x0, x1, 29); tf_round(x0, x1, 16); tf_round(x0, x1, 24);
  x0 += ks2; x1 += ks0 + 2u;
  tf_round(x0, x1, 13); tf_round(x0, x1, 15); tf_round(x0, x1, 26); tf_round(x0, x1, 6);
  x0 += ks0; x1 += ks1 + 3u;
  tf_round(x0, x1, 17); tf_round(x0, x1, 29); tf_round(x0, x1, 16); tf_round(x0, x1, 24);
  x0 += ks1; x1 += ks2 + 4u;
  tf_round(x0, x1, 13); tf_round(x0, x1, 15); tf_round(x0, x1, 26); tf_round(x0, x1, 6);
  x0 += ks2; x1 += ks0 + 5u;
  u[t]       = __uint_as_float((x0 >> 9) | 0x3f800000u) - 1.0f;
  u[t + 512] = __uint_as_float((x1 >> 9) | 0x3f800000u) - 1.0f;
  __syncthreads();
  if (t < BB) {
    int lb = labels[t];
    float best = -1.0f;
    int bj = 0;
    for (int j = 0; j < BB; ++j) {
      float v = (labels[j] != lb) ? u[t * BB + j] : -1.0f;
      if (v > best) { best = v; bj = j; }
    }
    negidx[t] = bj;
  }
}

// ---------------------------------------------------------------------------
// Kernel 4: pos/neg similarity + loss, mean-reduced into d_out[0].
// (q_grid/k_grid are unit-norm after l2norm, so cos_sim denom == 1 to ~1e-7.)
// ---------------------------------------------------------------------------
__global__ __launch_bounds__(256) void loss_kernel(
    const float* __restrict__ qg, const float* __restrict__ kg,
    const float* __restrict__ invq, const float* __restrict__ invk,
    const int* __restrict__ amax, const int* __restrict__ negidx,
    float* __restrict__ out) {
  int t = blockIdx.x * 256 + threadIdx.x;  // b*S+s
  int b = t >> 10;
  int s = t & (SS - 1);
  int js = amax[t];
  int nb = negidx[b];
  const float* qcol = qg + (size_t)b * CC * SS + s;
  const float* kpcol = kg + (size_t)b * CC * SS + js;
  const float* kncol = kg + (size_t)nb * CC * SS + s;
  float dp = 0.f, dn = 0.f;
#pragma unroll 8
  for (int c = 0; c < CC; ++c) {
    float q = qcol[(size_t)c * SS];
    dp = fmaf(q, kpcol[(size_t)c * SS], dp);
    dn = fmaf(q, kncol[(size_t)c * SS], dn);
  }
  float iq = invq[t];
  float p = dp * iq * invk[b * SS + js] * 10.0f;
  float n = dn * iq * invk[nb * SS + s] * 10.0f;
  float elem = logf(expf(p) + expf(n) + 1e-6f) - p;

  __shared__ float red[256];
  red[threadIdx.x] = elem;
  __syncthreads();
  for (int o = 128; o > 0; o >>= 1) {
    if (threadIdx.x < o) red[threadIdx.x] += red[threadIdx.x + o];
    __syncthreads();
  }
  if (threadIdx.x == 0) atomicAdd(out, red[0] * (1.0f / (BB * SS)));
}

// ---------------------------------------------------------------------------
extern "C" void kernel_launch(void* const* d_in, const int* in_sizes, int n_in,
                              void* d_out, int out_size, void* d_ws, size_t ws_size,
                              hipStream_t stream) {
  const float* qb = (const float*)d_in[0];
  const float* kb = (const float*)d_in[1];
  const float* qg = (const float*)d_in[2];
  const float* kg = (const float*)d_in[3];
  const int* labels = (const int*)d_in[4];

  float* inv = (float*)d_ws;                                   // 4 * B*S floats
  int* amax = (int*)((char*)d_ws + 4 * BB * SS * sizeof(float)); // B*S ints
  int* negidx = amax + BB * SS;                                 // B ints

  hipMemsetAsync(d_out, 0, sizeof(float), stream);

  norms_kernel<<<(4 * BB * SS) / 256, 256, 0, stream>>>(qb, kb, qg, kg, inv);
  simargmax_kernel<<<BB * (SS / TI), 256, 0, stream>>>(
      qb, kb, inv + 0 * BB * SS, inv + 1 * BB * SS, amax);
  negidx_kernel<<<1, 512, 0, stream>>>(labels, negidx);
  loss_kernel<<<(BB * SS) / 256, 256, 0, stream>>>(
      qg, kg, inv + 2 * BB * SS, inv + 3 * BB * SS, amax, negidx, (float*)d_out);
}

// Round 2
// 273.808 us; speedup vs baseline: 1.7092x; 1.7092x over previous
//
#include <hip/hip_runtime.h>
#include <hip/hip_bf16.h>
#include <math.h>
#include <stdint.h>

#define BB 32
#define CC 256
#define SS 1024
// TEMP = 0.1 -> multiply by 10

typedef __attribute__((ext_vector_type(8))) short short8v;
typedef __attribute__((ext_vector_type(4))) float f32x4;

#define ASYNC16(g, l)                                                        \
  __builtin_amdgcn_global_load_lds(                                          \
      (const __attribute__((address_space(1))) void*)(g),                    \
      (__attribute__((address_space(3))) void*)(l), 16, 0, 0)

// ---------------------------------------------------------------------------
// Kernel 1: inverse L2 norms along C for all four tensors.
// inv layout: [4][B*S]  (0=q_b, 1=k_b, 2=q_grid, 3=k_grid)
// ---------------------------------------------------------------------------
__global__ __launch_bounds__(256) void norms_kernel(
    const float* __restrict__ qb, const float* __restrict__ kb,
    const float* __restrict__ qg, const float* __restrict__ kg,
    float* __restrict__ inv) {
  int t = blockIdx.x * 256 + threadIdx.x;
  int which = t >> 15;
  int bs = t & (BB * SS - 1);
  const float* src = (which == 0) ? qb : (which == 1) ? kb : (which == 2) ? qg : kg;
  int b = bs >> 10;
  int s = bs & (SS - 1);
  const float* p = src + (size_t)b * CC * SS + s;
  float ss = 0.f;
#pragma unroll 8
  for (int c = 0; c < CC; ++c) {
    float x = p[(size_t)c * SS];
    ss = fmaf(x, x, ss);
  }
  float n = fmaxf(sqrtf(ss), 1e-12f);
  inv[t] = 1.0f / n;
}

// ---------------------------------------------------------------------------
// Kernel 2 (fast path): transpose qb, kb [C][S] f32 -> [S][C] bf16 (RNE), raw.
// One thread per s: reads coalesced over s (lanes = consecutive s), writes
// 16B rows; L2 write-combines the strided stores.
// Grid: 2 tensors * 32 b * 4 strips = 256 blocks.
// ---------------------------------------------------------------------------
__device__ __forceinline__ unsigned short bf16_rne(float f) {
  unsigned int u = __float_as_uint(f);
  unsigned int r = (u + 0x7fffu + ((u >> 16) & 1u)) >> 16;
  return (unsigned short)r;
}

__global__ __launch_bounds__(256) void trans_kernel(
    const float* __restrict__ qb, const float* __restrict__ kb,
    unsigned short* __restrict__ qt, unsigned short* __restrict__ kt) {
  int bid = blockIdx.x;
  int which = bid >> 7;
  int b = (bid >> 2) & 31;
  int s = (bid & 3) * 256 + threadIdx.x;
  const float* src = ((which) ? kb : qb) + (size_t)b * CC * SS + s;
  unsigned short* dst = ((which) ? kt : qt) + ((size_t)b * SS + s) * CC;
#pragma unroll 2
  for (int c0 = 0; c0 < CC; c0 += 8) {
    unsigned short u[8];
#pragma unroll
    for (int j = 0; j < 8; ++j) u[j] = bf16_rne(src[(size_t)(c0 + j) << 10]);
    uint4 pk;
    pk.x = (unsigned)u[0] | ((unsigned)u[1] << 16);
    pk.y = (unsigned)u[2] | ((unsigned)u[3] << 16);
    pk.z = (unsigned)u[4] | ((unsigned)u[5] << 16);
    pk.w = (unsigned)u[6] | ((unsigned)u[7] << 16);
    *(uint4*)(dst + c0) = pk;
  }
}

// ---------------------------------------------------------------------------
// Kernel 3 (fast path): bf16 MFMA sim + fused row-argmax.
// 128x128 tile per block, 4 waves, each 64x64 (4x4 of 16x16x32 mfma).
// Staging: global_load_lds 16B with XOR swizzle on 16B chunks (chunk^=(row&7))
// so fragment ds_read_b128 hits the 8-phase LDS floor.
// invk applied in fp32 at scan time (argmax over j of dot*invk[j]).
// Output: atomicMax of packed (sortable(val)<<32 | (1023-j)) per row.
// ---------------------------------------------------------------------------
__global__ __launch_bounds__(256) void simargmax_mfma(
    const unsigned short* __restrict__ qt, const unsigned short* __restrict__ kt,
    const float* __restrict__ invk, unsigned long long* __restrict__ best) {
  const int bid = blockIdx.x;
  const int b = bid >> 6, it = (bid >> 3) & 7, jt = bid & 7;
  const int t = threadIdx.x, w = t >> 6, l = t & 63;

  __shared__ union {
    struct { unsigned short a[128 * 64]; unsigned short b[128 * 64]; } st;
    float rb[128 * 68];  // [col][row] pitch 68 (16B-aligned cols)
  } sm;
  __shared__ unsigned long long cand[64][4];
  __shared__ float sinvk[128];

  if (t < 128) sinvk[t] = invk[b * SS + jt * 128 + t];

  const unsigned short* aG = qt + ((size_t)b * SS + it * 128) * CC;
  const unsigned short* bG = kt + ((size_t)b * SS + jt * 128) * CC;

  f32x4 acc[4][4];
#pragma unroll
  for (int mt = 0; mt < 4; ++mt)
#pragma unroll
    for (int nt = 0; nt < 4; ++nt) acc[mt][nt] = (f32x4){0.f, 0.f, 0.f, 0.f};

  const int r8 = l >> 3, p = l & 7;
  const int q4 = l >> 4, m16 = l & 15;
  const int wi = (w >> 1) * 64, wj = (w & 1) * 64;

  for (int ch = 0; ch < 4; ++ch) {
    __syncthreads();
    // stage A,B: 4 issues each, 16B/lane; wave covers 8 rows (128B) per issue
#pragma unroll
    for (int v = 0; v < 4; ++v) {
      int r = v * 32 + w * 8 + r8;
      int clog = p ^ (r & 7);  // logical chunk that lands in phys slot p
      ASYNC16(aG + (size_t)r * CC + ch * 64 + clog * 8,
              &sm.st.a[(v * 32 + w * 8) * 64]);
      ASYNC16(bG + (size_t)r * CC + ch * 64 + clog * 8,
              &sm.st.b[(v * 32 + w * 8) * 64]);
    }
    __syncthreads();
#pragma unroll
    for (int kk = 0; kk < 2; ++kk) {
      short8v af[4], bf[4];
#pragma unroll
      for (int mt = 0; mt < 4; ++mt) {
        int i = wi + mt * 16 + m16;
        int cp = (kk * 4 + q4) ^ (i & 7);  // phys chunk for logical kk*4+q4
        af[mt] = *(const short8v*)&sm.st.a[i * 64 + cp * 8];
        int j = wj + mt * 16 + m16;
        int cq = (kk * 4 + q4) ^ (j & 7);
        bf[mt] = *(const short8v*)&sm.st.b[j * 64 + cq * 8];
      }
#pragma unroll
      for (int mt = 0; mt < 4; ++mt)
#pragma unroll
        for (int nt = 0; nt < 4; ++nt)
          acc[mt][nt] = __builtin_amdgcn_mfma_f32_16x16x32_bf16(
              af[mt], bf[nt], acc[mt][nt], 0, 0, 0);
    }
  }

  // ---- epilogue: two half-phases (rows 0-63, 64-127) through rowbuf ----
  const int base_i = b * SS + it * 128;
  for (int half = 0; half < 2; ++half) {
    __syncthreads();
    if ((w >> 1) == half) {
#pragma unroll
      for (int mt = 0; mt < 4; ++mt) {
        int rowl = mt * 16 + q4 * 4;  // 4 consecutive rows per f32x4
#pragma unroll
        for (int nt = 0; nt < 4; ++nt) {
          int col = wj + nt * 16 + m16;
          *(f32x4*)&sm.rb[col * 68 + rowl] = acc[mt][nt];
        }
      }
    }
    __syncthreads();
    {
      // lane l = row, wave w = column part (cols w*32 .. w*32+31)
      float bv = -3.4e38f;
      int bc = 0;
#pragma unroll 8
      for (int c = 0; c < 32; ++c) {
        int col = w * 32 + c;
        float v = sm.rb[col * 68 + l] * sinvk[col];
        if (v > bv) { bv = v; bc = col; }
      }
      unsigned int u = __float_as_uint(bv);
      u = (u & 0x80000000u) ? ~u : (u | 0x80000000u);
      int jglob = jt * 128 + bc;
      cand[l][w] = ((unsigned long long)u << 32) | (unsigned)(1023 - jglob);
    }
    __syncthreads();
    if (t < 64) {
      unsigned long long m0 = cand[t][0];
#pragma unroll
      for (int pp = 1; pp < 4; ++pp) {
        unsigned long long c2 = cand[t][pp];
        if (c2 > m0) m0 = c2;
      }
      atomicMax(&best[base_i + half * 64 + t], m0);
    }
  }
}

// ---------------------------------------------------------------------------
// Kernel 3b: packed best -> int argmax index
// ---------------------------------------------------------------------------
__global__ void pack2idx_kernel(const unsigned long long* __restrict__ best,
                                int* __restrict__ amax) {
  int t = blockIdx.x * 256 + threadIdx.x;
  amax[t] = 1023 - (int)(best[t] & 0xffffffffu);
}

// ---------------------------------------------------------------------------
// Fallback (ws too small): round-1 fp32 VALU sim+argmax (known correct).
// ---------------------------------------------------------------------------
#define TI 64
#define TJ 128
#define KC 32

__global__ __launch_bounds__(256) void simargmax_kernel(
    const float* __restrict__ qb, const float* __restrict__ kb,
    const float* __restrict__ invq, const float* __restrict__ invk,
    int* __restrict__ amax) {
  const int b = blockIdx.x >> 4;
  const int i0 = (blockIdx.x & 15) * TI;
  const int t = threadIdx.x;
  const int ti = t >> 4;
  const int tj = t & 15;

  __shared__ float aQ[KC][TI];
  __shared__ float bK[KC][TJ];
  __shared__ float redv[TI][16];
  __shared__ int redj[TI][16];

  const float* qbase = qb + (size_t)b * CC * SS + i0;
  const float* kbase = kb + (size_t)b * CC * SS;
  const float* ivq = invq + b * SS + i0;
  const float* ivk = invk + b * SS;

  float best_v = -3.4e38f;
  int best_j = 0;

  for (int j0 = 0; j0 < SS; j0 += TJ) {
    float acc[4][8];
#pragma unroll
    for (int r = 0; r < 4; ++r)
#pragma unroll
      for (int rr = 0; rr < 8; ++rr) acc[r][rr] = 0.f;

    for (int c0 = 0; c0 < CC; c0 += KC) {
      __syncthreads();
#pragma unroll
      for (int v = 0; v < 2; ++v) {
        int f = t + v * 256;
        int cl = f >> 4;
        int sl = (f & 15) << 2;
        float4 qa = *(const float4*)(qbase + (size_t)(c0 + cl) * SS + sl);
        float4 iv = *(const float4*)(ivq + sl);
        aQ[cl][sl + 0] = qa.x * iv.x;
        aQ[cl][sl + 1] = qa.y * iv.y;
        aQ[cl][sl + 2] = qa.z * iv.z;
        aQ[cl][sl + 3] = qa.w * iv.w;
      }
#pragma unroll
      for (int v = 0; v < 4; ++v) {
        int f = t + v * 256;
        int cl = f >> 5;
        int sl = (f & 31) << 2;
        float4 ka = *(const float4*)(kbase + (size_t)(c0 + cl) * SS + j0 + sl);
        float4 ik = *(const float4*)(ivk + j0 + sl);
        bK[cl][sl + 0] = ka.x * ik.x;
        bK[cl][sl + 1] = ka.y * ik.y;
        bK[cl][sl + 2] = ka.z * ik.z;
        bK[cl][sl + 3] = ka.w * ik.w;
      }
      __syncthreads();
#pragma unroll
      for (int kc = 0; kc < KC; ++kc) {
        float4 a0 = *(const float4*)&aQ[kc][ti * 4];
        float4 b0 = *(const float4*)&bK[kc][tj * 8];
        float4 b1 = *(const float4*)&bK[kc][tj * 8 + 4];
        float av[4] = {a0.x, a0.y, a0.z, a0.w};
        float bv[8] = {b0.x, b0.y, b0.z, b0.w, b1.x, b1.y, b1.z, b1.w};
#pragma unroll
        for (int r = 0; r < 4; ++r)
#pragma unroll
          for (int rr = 0; rr < 8; ++rr)
            acc[r][rr] = fmaf(av[r], bv[rr], acc[r][rr]);
      }
    }
    __syncthreads();
#pragma unroll
    for (int r = 0; r < 4; ++r) {
      float v = acc[r][0];
      int jb = j0 + tj * 8;
#pragma unroll
      for (int rr = 1; rr < 8; ++rr) {
        if (acc[r][rr] > v) { v = acc[r][rr]; jb = j0 + tj * 8 + rr; }
      }
      redv[ti * 4 + r][tj] = v;
      redj[ti * 4 + r][tj] = jb;
    }
    __syncthreads();
    if (t < TI) {
#pragma unroll
      for (int ww = 0; ww < 16; ++ww) {
        float v = redv[t][ww];
        if (v > best_v) { best_v = v; best_j = redj[t][ww]; }
      }
    }
  }
  if (t < TI) amax[b * SS + i0 + t] = best_j;
}

// ---------------------------------------------------------------------------
// Kernel 4: Threefry-2x32-20 (JAX key(42), iota(1024)) -> u[32][32];
// neg_idx[b] = argmax_j( labels[b]!=labels[j] ? u[b][j] : -1 )
// ---------------------------------------------------------------------------
__device__ __forceinline__ void tf_round(uint32_t& x0, uint32_t& x1, int r) {
  x0 += x1;
  x1 = (x1 << r) | (x1 >> (32 - r));
  x1 ^= x0;
}

__global__ void negidx_kernel(const int* __restrict__ labels, int* __restrict__ negidx) {
  __shared__ float u[1024];
  int t = threadIdx.x;
  uint32_t x0 = (uint32_t)t;
  uint32_t x1 = (uint32_t)(t + 512);
  const uint32_t ks0 = 0u, ks1 = 42u, ks2 = 0x1BD11BDAu ^ 0u ^ 42u;
  x0 += ks0; x1 += ks1;
  tf_round(x0, x1, 13); tf_round(x0, x1, 15); tf_round(x0, x1, 26); tf_round(x0, x1, 6);
  x0 += ks1; x1 += ks2 + 1u;
  tf_round(x0, x1, 17); tf_round(x0, x1, 29); tf_round(x0, x1, 16); tf_round(x0, x1, 24);
  x0 += ks2; x1 += ks0 + 2u;
  tf_round(x0, x1, 13); tf_round(x0, x1, 15); tf_round(x0, x1, 26); tf_round(x0, x1, 6);
  x0 += ks0; x1 += ks1 + 3u;
  tf_round(x0, x1, 17); tf_round(x0, x1, 29); tf_round(x0, x1, 16); tf_round(x0, x1, 24);
  x0 += ks1; x1 += ks2 + 4u;
  tf_round(x0, x1, 13); tf_round(x0, x1, 15); tf_round(x0, x1, 26); tf_round(x0, x1, 6);
  x0 += ks2; x1 += ks0 + 5u;
  u[t]       = __uint_as_float((x0 >> 9) | 0x3f800000u) - 1.0f;
  u[t + 512] = __uint_as_float((x1 >> 9) | 0x3f800000u) - 1.0f;
  __syncthreads();
  if (t < BB) {
    int lb = labels[t];
    float best = -1.0f;
    int bj = 0;
    for (int j = 0; j < BB; ++j) {
      float v = (labels[j] != lb) ? u[t * BB + j] : -1.0f;
      if (v > best) { best = v; bj = j; }
    }
    negidx[t] = bj;
  }
}

// ---------------------------------------------------------------------------
// Kernel 5: pos/neg similarity + loss, mean-reduced into d_out[0].
// ---------------------------------------------------------------------------
__global__ __launch_bounds__(256) void loss_kernel(
    const float* __restrict__ qg, const float* __restrict__ kg,
    const float* __restrict__ invq, const float* __restrict__ invk,
    const int* __restrict__ amax, const int* __restrict__ negidx,
    float* __restrict__ out) {
  int t = blockIdx.x * 256 + threadIdx.x;
  int b = t >> 10;
  int s = t & (SS - 1);
  int js = amax[t];
  int nb = negidx[b];
  const float* qcol = qg + (size_t)b * CC * SS + s;
  const float* kpcol = kg + (size_t)b * CC * SS + js;
  const float* kncol = kg + (size_t)nb * CC * SS + s;
  float dp = 0.f, dn = 0.f;
#pragma unroll 8
  for (int c = 0; c < CC; ++c) {
    float q = qcol[(size_t)c * SS];
    dp = fmaf(q, kpcol[(size_t)c * SS], dp);
    dn = fmaf(q, kncol[(size_t)c * SS], dn);
  }
  float iq = invq[t];
  float pv = dp * iq * invk[b * SS + js] * 10.0f;
  float nv = dn * iq * invk[nb * SS + s] * 10.0f;
  float elem = logf(expf(pv) + expf(nv) + 1e-6f) - pv;

  __shared__ float red[256];
  red[threadIdx.x] = elem;
  __syncthreads();
  for (int o = 128; o > 0; o >>= 1) {
    if (threadIdx.x < o) red[threadIdx.x] += red[threadIdx.x + o];
    __syncthreads();
  }
  if (threadIdx.x == 0) atomicAdd(out, red[0] * (1.0f / (BB * SS)));
}

// ---------------------------------------------------------------------------
extern "C" void kernel_launch(void* const* d_in, const int* in_sizes, int n_in,
                              void* d_out, int out_size, void* d_ws, size_t ws_size,
                              hipStream_t stream) {
  const float* qb = (const float*)d_in[0];
  const float* kb = (const float*)d_in[1];
  const float* qg = (const float*)d_in[2];
  const float* kg = (const float*)d_in[3];
  const int* labels = (const int*)d_in[4];

  char* ws = (char*)d_ws;
  float* inv = (float*)ws;                                    // 512 KB
  int* amax = (int*)(ws + 512 * 1024);                        // 128 KB
  int* negidx = (int*)(ws + 640 * 1024);                      // 4 KB pad
  unsigned long long* best = (unsigned long long*)(ws + 704 * 1024);  // 256 KB
  unsigned short* qt = (unsigned short*)(ws + (1 << 20));     // 16 MB
  unsigned short* kt = (unsigned short*)(ws + (17 << 20));    // 16 MB

  const size_t need = (size_t)33 * 1024 * 1024;
  const bool fast = ws_size >= need;

  hipMemsetAsync(d_out, 0, sizeof(float), stream);

  norms_kernel<<<(4 * BB * SS) / 256, 256, 0, stream>>>(qb, kb, qg, kg, inv);

  if (fast) {
    hipMemsetAsync(best, 0, BB * SS * sizeof(unsigned long long), stream);
    trans_kernel<<<256, 256, 0, stream>>>(qb, kb, qt, kt);
    simargmax_mfma<<<2048, 256, 0, stream>>>(qt, kt, inv + 1 * BB * SS, best);
    pack2idx_kernel<<<(BB * SS) / 256, 256, 0, stream>>>(best, amax);
  } else {
    simargmax_kernel<<<BB * (SS / TI), 256, 0, stream>>>(
        qb, kb, inv + 0 * BB * SS, inv + 1 * BB * SS, amax);
  }

  negidx_kernel<<<1, 512, 0, stream>>>(labels, negidx);
  loss_kernel<<<(BB * SS) / 256, 256, 0, stream>>>(
      qg, kg, inv + 2 * BB * SS, inv + 3 * BB * SS, amax, negidx, (float*)d_out);
}

// Round 3
// 270.574 us; speedup vs baseline: 1.7296x; 1.0120x over previous
//
#include <hip/hip_runtime.h>
#include <hip/hip_bf16.h>
#include <math.h>
#include <stdint.h>

#define BB 32
#define CC 256
#define SS 1024
// TEMP = 0.1 -> multiply by 10

typedef __attribute__((ext_vector_type(8))) short short8v;
typedef __attribute__((ext_vector_type(4))) float f32x4;

#define ASYNC16(g, l)                                                        \
  __builtin_amdgcn_global_load_lds(                                          \
      (const __attribute__((address_space(1))) void*)(g),                    \
      (__attribute__((address_space(3))) void*)(l), 16, 0, 0)

__device__ __forceinline__ unsigned short bf16_rne(float f) {
  unsigned int u = __float_as_uint(f);
  unsigned int r = (u + 0x7fffu + ((u >> 16) & 1u)) >> 16;
  return (unsigned short)r;
}

// ---------------------------------------------------------------------------
// Fast kernel 1: qb,kb [C][S] f32 -> [S][C] bf16 transpose; kb inverse norms
// computed in the same pass (qb norms are never needed: row-constant scale is
// argmax-invariant). Grid: 2 tensors * 32 b * 4 strips = 256 blocks.
// ---------------------------------------------------------------------------
__global__ __launch_bounds__(256) void fuse_qbkb_kernel(
    const float* __restrict__ qb, const float* __restrict__ kb,
    unsigned short* __restrict__ qt, unsigned short* __restrict__ kt,
    float* __restrict__ invkb) {
  int bid = blockIdx.x;
  int which = bid >> 7;
  int b = (bid >> 2) & 31;
  int s = (bid & 3) * 256 + threadIdx.x;
  const float* src = ((which) ? kb : qb) + (size_t)b * CC * SS + s;
  unsigned short* dst = ((which) ? kt : qt) + ((size_t)b * SS + s) * CC;
  float ssq = 0.f;
#pragma unroll 2
  for (int c0 = 0; c0 < CC; c0 += 8) {
    unsigned short u[8];
#pragma unroll
    for (int j = 0; j < 8; ++j) {
      float x = src[(size_t)(c0 + j) << 10];
      ssq = fmaf(x, x, ssq);
      u[j] = bf16_rne(x);
    }
    uint4 pk;
    pk.x = (unsigned)u[0] | ((unsigned)u[1] << 16);
    pk.y = (unsigned)u[2] | ((unsigned)u[3] << 16);
    pk.z = (unsigned)u[4] | ((unsigned)u[5] << 16);
    pk.w = (unsigned)u[6] | ((unsigned)u[7] << 16);
    *(uint4*)(dst + c0) = pk;
  }
  if (which) invkb[b * SS + s] = 1.0f / fmaxf(sqrtf(ssq), 1e-12f);
}

// ---------------------------------------------------------------------------
// Fast kernel 2: kg [C][S] f32 -> [S][C] bf16 (kgt, aliases qt region; runs
// AFTER simargmax on the same stream) + kg inverse norms. Grid: 128 blocks.
// ---------------------------------------------------------------------------
__global__ __launch_bounds__(256) void fuse_kg_kernel(
    const float* __restrict__ kg, unsigned short* __restrict__ kgt,
    float* __restrict__ invkg) {
  int b = blockIdx.x >> 2;
  int s = (blockIdx.x & 3) * 256 + threadIdx.x;
  const float* src = kg + (size_t)b * CC * SS + s;
  unsigned short* dst = kgt + ((size_t)b * SS + s) * CC;
  float ssq = 0.f;
#pragma unroll 2
  for (int c0 = 0; c0 < CC; c0 += 8) {
    unsigned short u[8];
#pragma unroll
    for (int j = 0; j < 8; ++j) {
      float x = src[(size_t)(c0 + j) << 10];
      ssq = fmaf(x, x, ssq);
      u[j] = bf16_rne(x);
    }
    uint4 pk;
    pk.x = (unsigned)u[0] | ((unsigned)u[1] << 16);
    pk.y = (unsigned)u[2] | ((unsigned)u[3] << 16);
    pk.z = (unsigned)u[4] | ((unsigned)u[5] << 16);
    pk.w = (unsigned)u[6] | ((unsigned)u[7] << 16);
    *(uint4*)(dst + c0) = pk;
  }
  invkg[b * SS + s] = 1.0f / fmaxf(sqrtf(ssq), 1e-12f);
}

// ---------------------------------------------------------------------------
// Fast kernel 3: bf16 MFMA sim + fused row-argmax (unchanged from round 2).
// ---------------------------------------------------------------------------
__global__ __launch_bounds__(256) void simargmax_mfma(
    const unsigned short* __restrict__ qt, const unsigned short* __restrict__ kt,
    const float* __restrict__ invk, unsigned long long* __restrict__ best) {
  const int bid = blockIdx.x;
  const int b = bid >> 6, it = (bid >> 3) & 7, jt = bid & 7;
  const int t = threadIdx.x, w = t >> 6, l = t & 63;

  __shared__ union {
    struct { unsigned short a[128 * 64]; unsigned short b[128 * 64]; } st;
    float rb[128 * 68];
  } sm;
  __shared__ unsigned long long cand[64][4];
  __shared__ float sinvk[128];

  if (t < 128) sinvk[t] = invk[b * SS + jt * 128 + t];

  const unsigned short* aG = qt + ((size_t)b * SS + it * 128) * CC;
  const unsigned short* bG = kt + ((size_t)b * SS + jt * 128) * CC;

  f32x4 acc[4][4];
#pragma unroll
  for (int mt = 0; mt < 4; ++mt)
#pragma unroll
    for (int nt = 0; nt < 4; ++nt) acc[mt][nt] = (f32x4){0.f, 0.f, 0.f, 0.f};

  const int r8 = l >> 3, p = l & 7;
  const int q4 = l >> 4, m16 = l & 15;
  const int wi = (w >> 1) * 64, wj = (w & 1) * 64;

  for (int ch = 0; ch < 4; ++ch) {
    __syncthreads();
#pragma unroll
    for (int v = 0; v < 4; ++v) {
      int r = v * 32 + w * 8 + r8;
      int clog = p ^ (r & 7);
      ASYNC16(aG + (size_t)r * CC + ch * 64 + clog * 8,
              &sm.st.a[(v * 32 + w * 8) * 64]);
      ASYNC16(bG + (size_t)r * CC + ch * 64 + clog * 8,
              &sm.st.b[(v * 32 + w * 8) * 64]);
    }
    __syncthreads();
#pragma unroll
    for (int kk = 0; kk < 2; ++kk) {
      short8v af[4], bf[4];
#pragma unroll
      for (int mt = 0; mt < 4; ++mt) {
        int i = wi + mt * 16 + m16;
        int cp = (kk * 4 + q4) ^ (i & 7);
        af[mt] = *(const short8v*)&sm.st.a[i * 64 + cp * 8];
        int j = wj + mt * 16 + m16;
        int cq = (kk * 4 + q4) ^ (j & 7);
        bf[mt] = *(const short8v*)&sm.st.b[j * 64 + cq * 8];
      }
#pragma unroll
      for (int mt = 0; mt < 4; ++mt)
#pragma unroll
        for (int nt = 0; nt < 4; ++nt)
          acc[mt][nt] = __builtin_amdgcn_mfma_f32_16x16x32_bf16(
              af[mt], bf[nt], acc[mt][nt], 0, 0, 0);
    }
  }

  const int base_i = b * SS + it * 128;
  for (int half = 0; half < 2; ++half) {
    __syncthreads();
    if ((w >> 1) == half) {
#pragma unroll
      for (int mt = 0; mt < 4; ++mt) {
        int rowl = mt * 16 + q4 * 4;
#pragma unroll
        for (int nt = 0; nt < 4; ++nt) {
          int col = wj + nt * 16 + m16;
          *(f32x4*)&sm.rb[col * 68 + rowl] = acc[mt][nt];
        }
      }
    }
    __syncthreads();
    {
      float bv = -3.4e38f;
      int bc = 0;
#pragma unroll 8
      for (int c = 0; c < 32; ++c) {
        int col = w * 32 + c;
        float v = sm.rb[col * 68 + l] * sinvk[col];
        if (v > bv) { bv = v; bc = col; }
      }
      unsigned int u = __float_as_uint(bv);
      u = (u & 0x80000000u) ? ~u : (u | 0x80000000u);
      int jglob = jt * 128 + bc;
      cand[l][w] = ((unsigned long long)u << 32) | (unsigned)(1023 - jglob);
    }
    __syncthreads();
    if (t < 64) {
      unsigned long long m0 = cand[t][0];
#pragma unroll
      for (int pp = 1; pp < 4; ++pp) {
        unsigned long long c2 = cand[t][pp];
        if (c2 > m0) m0 = c2;
      }
      atomicMax(&best[base_i + half * 64 + t], m0);
    }
  }
}

// ---------------------------------------------------------------------------
// Kernel 4: Threefry-2x32-20 (JAX key(42), iota(1024)) -> u[32][32];
// neg_idx[b] = argmax_j( labels[b]!=labels[j] ? u[b][j] : -1 )
// ---------------------------------------------------------------------------
__device__ __forceinline__ void tf_round(uint32_t& x0, uint32_t& x1, int r) {
  x0 += x1;
  x1 = (x1 << r) | (x1 >> (32 - r));
  x1 ^= x0;
}

__global__ void negidx_kernel(const int* __restrict__ labels, int* __restrict__ negidx) {
  __shared__ float u[1024];
  int t = threadIdx.x;
  uint32_t x0 = (uint32_t)t;
  uint32_t x1 = (uint32_t)(t + 512);
  const uint32_t ks0 = 0u, ks1 = 42u, ks2 = 0x1BD11BDAu ^ 0u ^ 42u;
  x0 += ks0; x1 += ks1;
  tf_round(x0, x1, 13); tf_round(x0, x1, 15); tf_round(x0, x1, 26); tf_round(x0, x1, 6);
  x0 += ks1; x1 += ks2 + 1u;
  tf_round(x0, x1, 17); tf_round(x0, x1, 29); tf_round(x0, x1, 16); tf_round(x0, x1, 24);
  x0 += ks2; x1 += ks0 + 2u;
  tf_round(x0, x1, 13); tf_round(x0, x1, 15); tf_round(x0, x1, 26); tf_round(x0, x1, 6);
  x0 += ks0; x1 += ks1 + 3u;
  tf_round(x0, x1, 17); tf_round(x0, x1, 29); tf_round(x0, x1, 16); tf_round(x0, x1, 24);
  x0 += ks1; x1 += ks2 + 4u;
  tf_round(x0, x1, 13); tf_round(x0, x1, 15); tf_round(x0, x1, 26); tf_round(x0, x1, 6);
  x0 += ks2; x1 += ks0 + 5u;
  u[t]       = __uint_as_float((x0 >> 9) | 0x3f800000u) - 1.0f;
  u[t + 512] = __uint_as_float((x1 >> 9) | 0x3f800000u) - 1.0f;
  __syncthreads();
  if (t < BB) {
    int lb = labels[t];
    float best = -1.0f;
    int bj = 0;
    for (int j = 0; j < BB; ++j) {
      float v = (labels[j] != lb) ? u[t * BB + j] : -1.0f;
      if (v > best) { best = v; bj = j; }
    }
    negidx[t] = bj;
  }
}

// ---------------------------------------------------------------------------
// Fast kernel 5: fused loss. q_grid norms computed in-pass (fp32); matched /
// negative k read as contiguous bf16 rows from kgt; argmax index unpacked
// from `best` directly. Grid: 256 blocks x 128 threads (one thread per (b,s)).
// ---------------------------------------------------------------------------
__global__ __launch_bounds__(128) void loss_fused_kernel(
    const float* __restrict__ qg, const unsigned short* __restrict__ kgt,
    const float* __restrict__ invkg, const unsigned long long* __restrict__ best,
    const int* __restrict__ negidx, float* __restrict__ out) {
  int t = blockIdx.x * 128 + threadIdx.x;
  int b = t >> 10;
  int s = t & (SS - 1);
  int js = 1023 - (int)(best[t] & 0xffffffffu);
  int nb = negidx[b];
  const float* qcol = qg + (size_t)b * CC * SS + s;
  const unsigned short* kp = kgt + ((size_t)b * SS + js) * CC;
  const unsigned short* kn = kgt + ((size_t)nb * SS + s) * CC;
  float dp = 0.f, dn = 0.f, ssq = 0.f;
#pragma unroll 4
  for (int c0 = 0; c0 < CC; c0 += 8) {
    uint4 up = *(const uint4*)(kp + c0);
    uint4 un = *(const uint4*)(kn + c0);
    float q[8];
#pragma unroll
    for (int j = 0; j < 8; ++j) {
      q[j] = qcol[(size_t)(c0 + j) << 10];
      ssq = fmaf(q[j], q[j], ssq);
    }
    float pv[8], nv[8];
    pv[0] = __uint_as_float(up.x << 16); pv[1] = __uint_as_float(up.x & 0xffff0000u);
    pv[2] = __uint_as_float(up.y << 16); pv[3] = __uint_as_float(up.y & 0xffff0000u);
    pv[4] = __uint_as_float(up.z << 16); pv[5] = __uint_as_float(up.z & 0xffff0000u);
    pv[6] = __uint_as_float(up.w << 16); pv[7] = __uint_as_float(up.w & 0xffff0000u);
    nv[0] = __uint_as_float(un.x << 16); nv[1] = __uint_as_float(un.x & 0xffff0000u);
    nv[2] = __uint_as_float(un.y << 16); nv[3] = __uint_as_float(un.y & 0xffff0000u);
    nv[4] = __uint_as_float(un.z << 16); nv[5] = __uint_as_float(un.z & 0xffff0000u);
    nv[6] = __uint_as_float(un.w << 16); nv[7] = __uint_as_float(un.w & 0xffff0000u);
#pragma unroll
    for (int j = 0; j < 8; ++j) {
      dp = fmaf(q[j], pv[j], dp);
      dn = fmaf(q[j], nv[j], dn);
    }
  }
  float iq = 1.0f / fmaxf(sqrtf(ssq), 1e-12f);
  float p = dp * iq * invkg[b * SS + js] * 10.0f;
  float n = dn * iq * invkg[nb * SS + s] * 10.0f;
  float elem = logf(expf(p) + expf(n) + 1e-6f) - p;

  __shared__ float red[128];
  red[threadIdx.x] = elem;
  __syncthreads();
  for (int o = 64; o > 0; o >>= 1) {
    if (threadIdx.x < o) red[threadIdx.x] += red[threadIdx.x + o];
    __syncthreads();
  }
  if (threadIdx.x == 0) atomicAdd(out, red[0] * (1.0f / (BB * SS)));
}

// ===========================================================================
// Fallback path (ws too small): round-1 fp32 VALU, known correct.
// ===========================================================================
__global__ __launch_bounds__(256) void norms_kernel(
    const float* __restrict__ qb, const float* __restrict__ kb,
    const float* __restrict__ qg, const float* __restrict__ kg,
    float* __restrict__ inv) {
  int t = blockIdx.x * 256 + threadIdx.x;
  int which = t >> 15;
  int bs = t & (BB * SS - 1);
  const float* src = (which == 0) ? qb : (which == 1) ? kb : (which == 2) ? qg : kg;
  int b = bs >> 10;
  int s = bs & (SS - 1);
  const float* p = src + (size_t)b * CC * SS + s;
  float ss = 0.f;
#pragma unroll 8
  for (int c = 0; c < CC; ++c) {
    float x = p[(size_t)c * SS];
    ss = fmaf(x, x, ss);
  }
  float n = fmaxf(sqrtf(ss), 1e-12f);
  inv[t] = 1.0f / n;
}

#define TI 64
#define TJ 128
#define KC 32

__global__ __launch_bounds__(256) void simargmax_kernel(
    const float* __restrict__ qb, const float* __restrict__ kb,
    const float* __restrict__ invq, const float* __restrict__ invk,
    int* __restrict__ amax) {
  const int b = blockIdx.x >> 4;
  const int i0 = (blockIdx.x & 15) * TI;
  const int t = threadIdx.x;
  const int ti = t >> 4;
  const int tj = t & 15;

  __shared__ float aQ[KC][TI];
  __shared__ float bK[KC][TJ];
  __shared__ float redv[TI][16];
  __shared__ int redj[TI][16];

  const float* qbase = qb + (size_t)b * CC * SS + i0;
  const float* kbase = kb + (size_t)b * CC * SS;
  const float* ivq = invq + b * SS + i0;
  const float* ivk = invk + b * SS;

  float best_v = -3.4e38f;
  int best_j = 0;

  for (int j0 = 0; j0 < SS; j0 += TJ) {
    float acc[4][8];
#pragma unroll
    for (int r = 0; r < 4; ++r)
#pragma unroll
      for (int rr = 0; rr < 8; ++rr) acc[r][rr] = 0.f;

    for (int c0 = 0; c0 < CC; c0 += KC) {
      __syncthreads();
#pragma unroll
      for (int v = 0; v < 2; ++v) {
        int f = t + v * 256;
        int cl = f >> 4;
        int sl = (f & 15) << 2;
        float4 qa = *(const float4*)(qbase + (size_t)(c0 + cl) * SS + sl);
        float4 iv = *(const float4*)(ivq + sl);
        aQ[cl][sl + 0] = qa.x * iv.x;
        aQ[cl][sl + 1] = qa.y * iv.y;
        aQ[cl][sl + 2] = qa.z * iv.z;
        aQ[cl][sl + 3] = qa.w * iv.w;
      }
#pragma unroll
      for (int v = 0; v < 4; ++v) {
        int f = t + v * 256;
        int cl = f >> 5;
        int sl = (f & 31) << 2;
        float4 ka = *(const float4*)(kbase + (size_t)(c0 + cl) * SS + j0 + sl);
        float4 ik = *(const float4*)(ivk + j0 + sl);
        bK[cl][sl + 0] = ka.x * ik.x;
        bK[cl][sl + 1] = ka.y * ik.y;
        bK[cl][sl + 2] = ka.z * ik.z;
        bK[cl][sl + 3] = ka.w * ik.w;
      }
      __syncthreads();
#pragma unroll
      for (int kc = 0; kc < KC; ++kc) {
        float4 a0 = *(const float4*)&aQ[kc][ti * 4];
        float4 b0 = *(const float4*)&bK[kc][tj * 8];
        float4 b1 = *(const float4*)&bK[kc][tj * 8 + 4];
        float av[4] = {a0.x, a0.y, a0.z, a0.w};
        float bv[8] = {b0.x, b0.y, b0.z, b0.w, b1.x, b1.y, b1.z, b1.w};
#pragma unroll
        for (int r = 0; r < 4; ++r)
#pragma unroll
          for (int rr = 0; rr < 8; ++rr)
            acc[r][rr] = fmaf(av[r], bv[rr], acc[r][rr]);
      }
    }
    __syncthreads();
#pragma unroll
    for (int r = 0; r < 4; ++r) {
      float v = acc[r][0];
      int jb = j0 + tj * 8;
#pragma unroll
      for (int rr = 1; rr < 8; ++rr) {
        if (acc[r][rr] > v) { v = acc[r][rr]; jb = j0 + tj * 8 + rr; }
      }
      redv[ti * 4 + r][tj] = v;
      redj[ti * 4 + r][tj] = jb;
    }
    __syncthreads();
    if (t < TI) {
#pragma unroll
      for (int ww = 0; ww < 16; ++ww) {
        float v = redv[t][ww];
        if (v > best_v) { best_v = v; best_j = redj[t][ww]; }
      }
    }
  }
  if (t < TI) amax[b * SS + i0 + t] = best_j;
}

__global__ __launch_bounds__(256) void loss_kernel(
    const float* __restrict__ qg, const float* __restrict__ kg,
    const float* __restrict__ invq, const float* __restrict__ invk,
    const int* __restrict__ amax, const int* __restrict__ negidx,
    float* __restrict__ out) {
  int t = blockIdx.x * 256 + threadIdx.x;
  int b = t >> 10;
  int s = t & (SS - 1);
  int js = amax[t];
  int nb = negidx[b];
  const float* qcol = qg + (size_t)b * CC * SS + s;
  const float* kpcol = kg + (size_t)b * CC * SS + js;
  const float* kncol = kg + (size_t)nb * CC * SS + s;
  float dp = 0.f, dn = 0.f;
#pragma unroll 8
  for (int c = 0; c < CC; ++c) {
    float q = qcol[(size_t)c * SS];
    dp = fmaf(q, kpcol[(size_t)c * SS], dp);
    dn = fmaf(q, kncol[(size_t)c * SS], dn);
  }
  float iq = invq[t];
  float pv = dp * iq * invk[b * SS + js] * 10.0f;
  float nv = dn * iq * invk[nb * SS + s] * 10.0f;
  float elem = logf(expf(pv) + expf(nv) + 1e-6f) - pv;

  __shared__ float red[256];
  red[threadIdx.x] = elem;
  __syncthreads();
  for (int o = 128; o > 0; o >>= 1) {
    if (threadIdx.x < o) red[threadIdx.x] += red[threadIdx.x + o];
    __syncthreads();
  }
  if (threadIdx.x == 0) atomicAdd(out, red[0] * (1.0f / (BB * SS)));
}

// ---------------------------------------------------------------------------
extern "C" void kernel_launch(void* const* d_in, const int* in_sizes, int n_in,
                              void* d_out, int out_size, void* d_ws, size_t ws_size,
                              hipStream_t stream) {
  const float* qb = (const float*)d_in[0];
  const float* kb = (const float*)d_in[1];
  const float* qg = (const float*)d_in[2];
  const float* kg = (const float*)d_in[3];
  const int* labels = (const int*)d_in[4];

  char* ws = (char*)d_ws;
  // fast-path layout (33 MB total, proven available in round 2):
  float* invkb = (float*)ws;                                   // 128 KB
  float* invkg = (float*)(ws + 128 * 1024);                    // 128 KB
  unsigned long long* best = (unsigned long long*)(ws + 256 * 1024);  // 256 KB
  int* negidx = (int*)(ws + 512 * 1024);                       // small
  unsigned short* qt = (unsigned short*)(ws + (1 << 20));      // 16 MB
  unsigned short* kt = (unsigned short*)(ws + (17 << 20));     // 16 MB
  unsigned short* kgt = qt;  // aliases qt — written after simargmax (stream-serial)

  const size_t need = (size_t)33 * 1024 * 1024;
  const bool fast = ws_size >= need;

  hipMemsetAsync(d_out, 0, sizeof(float), stream);

  if (fast) {
    hipMemsetAsync(best, 0, BB * SS * sizeof(unsigned long long), stream);
    negidx_kernel<<<1, 512, 0, stream>>>(labels, negidx);
    fuse_qbkb_kernel<<<256, 256, 0, stream>>>(qb, kb, qt, kt, invkb);
    simargmax_mfma<<<2048, 256, 0, stream>>>(qt, kt, invkb, best);
    fuse_kg_kernel<<<128, 256, 0, stream>>>(kg, kgt, invkg);
    loss_fused_kernel<<<256, 128, 0, stream>>>(qg, kgt, invkg, best, negidx,
                                               (float*)d_out);
  } else {
    float* inv = (float*)ws;                                    // 512 KB
    int* amax = (int*)(ws + 512 * 1024);                        // 128 KB
    int* negidx2 = (int*)(ws + 640 * 1024);
    norms_kernel<<<(4 * BB * SS) / 256, 256, 0, stream>>>(qb, kb, qg, kg, inv);
    simargmax_kernel<<<BB * (SS / TI), 256, 0, stream>>>(
        qb, kb, inv + 0 * BB * SS, inv + 1 * BB * SS, amax);
    negidx_kernel<<<1, 512, 0, stream>>>(labels, negidx2);
    loss_kernel<<<(BB * SS) / 256, 256, 0, stream>>>(
        qg, kg, inv + 2 * BB * SS, inv + 3 * BB * SS, amax, negidx2,
        (float*)d_out);
  }
}

// Round 4
// 218.111 us; speedup vs baseline: 2.1457x; 1.2405x over previous
//
#include <hip/hip_runtime.h>
#include <hip/hip_bf16.h>
#include <math.h>
#include <stdint.h>

#define BB 32
#define CC 256
#define SS 1024
// TEMP = 0.1 -> multiply by 10

typedef __attribute__((ext_vector_type(8))) short short8v;
typedef __attribute__((ext_vector_type(4))) float f32x4;

#define ASYNC16(g, l)                                                        \
  __builtin_amdgcn_global_load_lds(                                          \
      (const __attribute__((address_space(1))) void*)(g),                    \
      (__attribute__((address_space(3))) void*)(l), 16, 0, 0)

__device__ __forceinline__ unsigned short bf16_rne(float f) {
  unsigned int u = __float_as_uint(f);
  unsigned int r = (u + 0x7fffu + ((u >> 16) & 1u)) >> 16;
  return (unsigned short)r;
}

// ---------------------------------------------------------------------------
// transnorm: [C][S] f32 -> [S][C] bf16 via LDS tile (coalesced both sides) +
// per-s inverse L2 norm over C. Block = (which, b, 32-s strip).
// Launch 1: grid 2048 -> which = bid>>10 (0: srcA, 1: srcB).
// Launch 2: grid 1024 -> which always 0.
// ---------------------------------------------------------------------------
__global__ __launch_bounds__(256, 4) void transnorm_kernel(
    const float* __restrict__ srcA, const float* __restrict__ srcB,
    unsigned short* __restrict__ dstA, unsigned short* __restrict__ dstB,
    float* __restrict__ invA, float* __restrict__ invB) {
  const int bid = blockIdx.x;
  const int which = bid >> 10;
  const int sub = bid & 1023;
  const int b = sub >> 5;
  const int s0 = (sub & 31) * 32;

  const float* src = which ? srcB : srcA;
  unsigned short* dst = which ? dstB : dstA;
  float* inv = which ? invB : invA;

  __shared__ float st[256][33];
  __shared__ float part[8][33];

  const int tid = threadIdx.x;
  const int s_l = tid & 31, c_off = tid >> 5;

  const float* sp = src + (size_t)b * CC * SS + s0 + s_l;
  float ssq = 0.f;
#pragma unroll 8
  for (int p = 0; p < 32; ++p) {
    int c = p * 8 + c_off;
    float x = sp[(size_t)c << 10];
    ssq = fmaf(x, x, ssq);
    st[c][s_l] = x;
  }
  part[c_off][s_l] = ssq;
  __syncthreads();

  // store phase: thread (chunk=tid>>3, r=tid&7 + r0), 8 consecutive c -> 16B
  const int chunk = tid >> 3, rb8 = tid & 7;
  unsigned short* dp = dst + ((size_t)b * SS + s0) * CC;
#pragma unroll
  for (int r0 = 0; r0 < 32; r0 += 8) {
    int r = r0 + rb8;
    unsigned short u[8];
#pragma unroll
    for (int uu = 0; uu < 8; ++uu) u[uu] = bf16_rne(st[chunk * 8 + uu][r]);
    uint4 pk;
    pk.x = (unsigned)u[0] | ((unsigned)u[1] << 16);
    pk.y = (unsigned)u[2] | ((unsigned)u[3] << 16);
    pk.z = (unsigned)u[4] | ((unsigned)u[5] << 16);
    pk.w = (unsigned)u[6] | ((unsigned)u[7] << 16);
    *(uint4*)(dp + (size_t)r * CC + chunk * 8) = pk;
  }
  if (tid < 32) {
    float s = 0.f;
#pragma unroll
    for (int k = 0; k < 8; ++k) s += part[k][tid];
    inv[b * SS + s0 + tid] = 1.0f / fmaxf(sqrtf(s), 1e-12f);
  }
}

// ---------------------------------------------------------------------------
// simargmax v3: bf16 MFMA sim + in-register row argmax.
// 128x128 tile, 4 waves x (4x4 of 16x16x32). LDS 35KB -> 3 blocks/CU.
// ---------------------------------------------------------------------------
__global__ __launch_bounds__(256, 3) void simargmax_mfma(
    const unsigned short* __restrict__ qt, const unsigned short* __restrict__ kt,
    const float* __restrict__ invk, unsigned long long* __restrict__ best) {
  const int bid = blockIdx.x;
  const int b = bid >> 6, it = (bid >> 3) & 7, jt = bid & 7;
  const int t = threadIdx.x, w = t >> 6, l = t & 63;

  __shared__ unsigned short sa[128 * 64];
  __shared__ unsigned short sb[128 * 64];
  __shared__ unsigned long long cand2[128][2];
  __shared__ float sinvk[128];

  if (t < 128) sinvk[t] = invk[b * SS + jt * 128 + t];

  const unsigned short* aG = qt + ((size_t)b * SS + it * 128) * CC;
  const unsigned short* bG = kt + ((size_t)b * SS + jt * 128) * CC;

  f32x4 acc[4][4];
#pragma unroll
  for (int mt = 0; mt < 4; ++mt)
#pragma unroll
    for (int nt = 0; nt < 4; ++nt) acc[mt][nt] = (f32x4){0.f, 0.f, 0.f, 0.f};

  const int r8 = l >> 3, p = l & 7;
  const int q4 = l >> 4, m16 = l & 15;
  const int wi = (w >> 1) * 64, wj = (w & 1) * 64;

  for (int ch = 0; ch < 4; ++ch) {
    __syncthreads();
#pragma unroll
    for (int v = 0; v < 4; ++v) {
      int r = v * 32 + w * 8 + r8;
      int clog = p ^ (r & 7);
      ASYNC16(aG + (size_t)r * CC + ch * 64 + clog * 8, &sa[(v * 32 + w * 8) * 64]);
      ASYNC16(bG + (size_t)r * CC + ch * 64 + clog * 8, &sb[(v * 32 + w * 8) * 64]);
    }
    __syncthreads();
#pragma unroll
    for (int kk = 0; kk < 2; ++kk) {
      short8v af[4], bf[4];
#pragma unroll
      for (int mt = 0; mt < 4; ++mt) {
        int i = wi + mt * 16 + m16;
        int cp = (kk * 4 + q4) ^ (i & 7);
        af[mt] = *(const short8v*)&sa[i * 64 + cp * 8];
        int j = wj + mt * 16 + m16;
        int cq = (kk * 4 + q4) ^ (j & 7);
        bf[mt] = *(const short8v*)&sb[j * 64 + cq * 8];
      }
#pragma unroll
      for (int mt = 0; mt < 4; ++mt)
#pragma unroll
        for (int nt = 0; nt < 4; ++nt)
          acc[mt][nt] = __builtin_amdgcn_mfma_f32_16x16x32_bf16(
              af[mt], bf[nt], acc[mt][nt], 0, 0, 0);
    }
  }

  // ---- in-register argmax ----
  // acc[mt][nt][e]: row = wi + mt*16 + q4*4 + e ; local col = wj + nt*16 + m16
  float siv[4];
#pragma unroll
  for (int nt = 0; nt < 4; ++nt) siv[nt] = sinvk[wj + nt * 16 + m16];

  unsigned long long bp[4][4];
#pragma unroll
  for (int mt = 0; mt < 4; ++mt) {
#pragma unroll
    for (int e = 0; e < 4; ++e) {
      unsigned long long mx = 0ull;
#pragma unroll
      for (int nt = 0; nt < 4; ++nt) {
        float v = acc[mt][nt][e] * siv[nt];
        unsigned int u = __float_as_uint(v);
        u = (u & 0x80000000u) ? ~u : (u | 0x80000000u);
        int col = jt * 128 + wj + nt * 16 + m16;
        unsigned long long pk =
            ((unsigned long long)u << 32) | (unsigned)(1023 - col);
        mx = (pk > mx) ? pk : mx;
      }
      bp[mt][e] = mx;
    }
  }
  // butterfly over the 16 column-lanes (m16); rows constant under l^d, d<16
#pragma unroll
  for (int d = 1; d < 16; d <<= 1) {
#pragma unroll
    for (int mt = 0; mt < 4; ++mt)
#pragma unroll
      for (int e = 0; e < 4; ++e) {
        unsigned long long o = __shfl_xor(bp[mt][e], d, 64);
        if (o > bp[mt][e]) bp[mt][e] = o;
      }
  }
  if (m16 == 0) {
#pragma unroll
    for (int mt = 0; mt < 4; ++mt)
#pragma unroll
      for (int e = 0; e < 4; ++e)
        cand2[wi + mt * 16 + q4 * 4 + e][w & 1] = bp[mt][e];
  }
  __syncthreads();
  if (t < 128) {
    unsigned long long m0 = cand2[t][0], m1 = cand2[t][1];
    atomicMax(&best[b * SS + it * 128 + t], m0 > m1 ? m0 : m1);
  }
}

// ---------------------------------------------------------------------------
// Threefry-2x32-20 (JAX key(42), iota(1024)) -> u[32][32]; neg_idx per b.
// ---------------------------------------------------------------------------
__device__ __forceinline__ void tf_round(uint32_t& x0, uint32_t& x1, int r) {
  x0 += x1;
  x1 = (x1 << r) | (x1 >> (32 - r));
  x1 ^= x0;
}

__global__ void negidx_kernel(const int* __restrict__ labels, int* __restrict__ negidx) {
  __shared__ float u[1024];
  int t = threadIdx.x;
  uint32_t x0 = (uint32_t)t;
  uint32_t x1 = (uint32_t)(t + 512);
  const uint32_t ks0 = 0u, ks1 = 42u, ks2 = 0x1BD11BDAu ^ 0u ^ 42u;
  x0 += ks0; x1 += ks1;
  tf_round(x0, x1, 13); tf_round(x0, x1, 15); tf_round(x0, x1, 26); tf_round(x0, x1, 6);
  x0 += ks1; x1 += ks2 + 1u;
  tf_round(x0, x1, 17); tf_round(x0, x1, 29); tf_round(x0, x1, 16); tf_round(x0, x1, 24);
  x0 += ks2; x1 += ks0 + 2u;
  tf_round(x0, x1, 13); tf_round(x0, x1, 15); tf_round(x0, x1, 26); tf_round(x0, x1, 6);
  x0 += ks0; x1 += ks1 + 3u;
  tf_round(x0, x1, 17); tf_round(x0, x1, 29); tf_round(x0, x1, 16); tf_round(x0, x1, 24);
  x0 += ks1; x1 += ks2 + 4u;
  tf_round(x0, x1, 13); tf_round(x0, x1, 15); tf_round(x0, x1, 26); tf_round(x0, x1, 6);
  x0 += ks2; x1 += ks0 + 5u;
  u[t]       = __uint_as_float((x0 >> 9) | 0x3f800000u) - 1.0f;
  u[t + 512] = __uint_as_float((x1 >> 9) | 0x3f800000u) - 1.0f;
  __syncthreads();
  if (t < BB) {
    int lb = labels[t];
    float bestv = -1.0f;
    int bj = 0;
    for (int j = 0; j < BB; ++j) {
      float v = (labels[j] != lb) ? u[t * BB + j] : -1.0f;
      if (v > bestv) { bestv = v; bj = j; }
    }
    negidx[t] = bj;
  }
}

// ---------------------------------------------------------------------------
// loss v2: 8 threads per (b,s); 1024 blocks x 256 threads (16 waves/CU).
// qg norms fused; k rows read as contiguous bf16 from kgt.
// ---------------------------------------------------------------------------
__global__ __launch_bounds__(256) void loss_fused_kernel(
    const float* __restrict__ qg, const unsigned short* __restrict__ kgt,
    const float* __restrict__ invkg, const unsigned long long* __restrict__ best,
    const int* __restrict__ negidx, float* __restrict__ out) {
  const int tid = threadIdx.x;
  const int s_l = tid & 31, g = tid >> 5;
  const int P0 = blockIdx.x * 32;
  const int b = P0 >> 10;
  const int s = (P0 & (SS - 1)) + s_l;
  const int idx = b * SS + s;
  const int js = 1023 - (int)(best[idx] & 0xffffffffu);
  const int nb = negidx[b];

  const float* qcol = qg + ((size_t)b * CC + g * 32) * SS + s;
  const unsigned short* kp = kgt + ((size_t)b * SS + js) * CC + g * 32;
  const unsigned short* kn = kgt + ((size_t)nb * SS + s) * CC + g * 32;

  float dp = 0.f, dn = 0.f, sq = 0.f;
#pragma unroll
  for (int uu = 0; uu < 4; ++uu) {
    uint4 up = *(const uint4*)(kp + uu * 8);
    uint4 un = *(const uint4*)(kn + uu * 8);
    float q[8];
#pragma unroll
    for (int j = 0; j < 8; ++j) {
      q[j] = qcol[(size_t)(uu * 8 + j) << 10];
      sq = fmaf(q[j], q[j], sq);
    }
    float pv[8], nv[8];
    pv[0] = __uint_as_float(up.x << 16); pv[1] = __uint_as_float(up.x & 0xffff0000u);
    pv[2] = __uint_as_float(up.y << 16); pv[3] = __uint_as_float(up.y & 0xffff0000u);
    pv[4] = __uint_as_float(up.z << 16); pv[5] = __uint_as_float(up.z & 0xffff0000u);
    pv[6] = __uint_as_float(up.w << 16); pv[7] = __uint_as_float(up.w & 0xffff0000u);
    nv[0] = __uint_as_float(un.x << 16); nv[1] = __uint_as_float(un.x & 0xffff0000u);
    nv[2] = __uint_as_float(un.y << 16); nv[3] = __uint_as_float(un.y & 0xffff0000u);
    nv[4] = __uint_as_float(un.z << 16); nv[5] = __uint_as_float(un.z & 0xffff0000u);
    nv[6] = __uint_as_float(un.w << 16); nv[7] = __uint_as_float(un.w & 0xffff0000u);
#pragma unroll
    for (int j = 0; j < 8; ++j) {
      dp = fmaf(q[j], pv[j], dp);
      dn = fmaf(q[j], nv[j], dn);
    }
  }

  __shared__ float rdp[8][33], rdn[8][33], rsq[8][33];
  rdp[g][s_l] = dp;
  rdn[g][s_l] = dn;
  rsq[g][s_l] = sq;
  __syncthreads();
  if (tid < 32) {
    float DP = 0.f, DN = 0.f, SQ = 0.f;
#pragma unroll
    for (int k = 0; k < 8; ++k) {
      DP += rdp[k][tid];
      DN += rdn[k][tid];
      SQ += rsq[k][tid];
    }
    int s2 = (P0 & (SS - 1)) + tid;
    int idx2 = b * SS + s2;
    int js2 = 1023 - (int)(best[idx2] & 0xffffffffu);
    float iq = 1.0f / fmaxf(sqrtf(SQ), 1e-12f);
    float pvv = DP * iq * invkg[b * SS + js2] * 10.0f;
    float nvv = DN * iq * invkg[nb * SS + s2] * 10.0f;
    float elem = logf(expf(pvv) + expf(nvv) + 1e-6f) - pvv;
#pragma unroll
    for (int o = 16; o > 0; o >>= 1) elem += __shfl_down(elem, o, 32);
    if (tid == 0) atomicAdd(out, elem * (1.0f / (BB * SS)));
  }
}

// ===========================================================================
// Fallback path (ws too small): round-1 fp32 VALU, known correct.
// ===========================================================================
__global__ __launch_bounds__(256) void norms_kernel(
    const float* __restrict__ qb, const float* __restrict__ kb,
    const float* __restrict__ qg, const float* __restrict__ kg,
    float* __restrict__ inv) {
  int t = blockIdx.x * 256 + threadIdx.x;
  int which = t >> 15;
  int bs = t & (BB * SS - 1);
  const float* src = (which == 0) ? qb : (which == 1) ? kb : (which == 2) ? qg : kg;
  int b = bs >> 10;
  int s = bs & (SS - 1);
  const float* p = src + (size_t)b * CC * SS + s;
  float ss = 0.f;
#pragma unroll 8
  for (int c = 0; c < CC; ++c) {
    float x = p[(size_t)c * SS];
    ss = fmaf(x, x, ss);
  }
  float n = fmaxf(sqrtf(ss), 1e-12f);
  inv[t] = 1.0f / n;
}

#define TI 64
#define TJ 128
#define KC 32

__global__ __launch_bounds__(256) void simargmax_kernel(
    const float* __restrict__ qb, const float* __restrict__ kb,
    const float* __restrict__ invq, const float* __restrict__ invk,
    int* __restrict__ amax) {
  const int b = blockIdx.x >> 4;
  const int i0 = (blockIdx.x & 15) * TI;
  const int t = threadIdx.x;
  const int ti = t >> 4;
  const int tj = t & 15;

  __shared__ float aQ[KC][TI];
  __shared__ float bK[KC][TJ];
  __shared__ float redv[TI][16];
  __shared__ int redj[TI][16];

  const float* qbase = qb + (size_t)b * CC * SS + i0;
  const float* kbase = kb + (size_t)b * CC * SS;
  const float* ivq = invq + b * SS + i0;
  const float* ivk = invk + b * SS;

  float best_v = -3.4e38f;
  int best_j = 0;

  for (int j0 = 0; j0 < SS; j0 += TJ) {
    float acc[4][8];
#pragma unroll
    for (int r = 0; r < 4; ++r)
#pragma unroll
      for (int rr = 0; rr < 8; ++rr) acc[r][rr] = 0.f;

    for (int c0 = 0; c0 < CC; c0 += KC) {
      __syncthreads();
#pragma unroll
      for (int v = 0; v < 2; ++v) {
        int f = t + v * 256;
        int cl = f >> 4;
        int sl = (f & 15) << 2;
        float4 qa = *(const float4*)(qbase + (size_t)(c0 + cl) * SS + sl);
        float4 iv = *(const float4*)(ivq + sl);
        aQ[cl][sl + 0] = qa.x * iv.x;
        aQ[cl][sl + 1] = qa.y * iv.y;
        aQ[cl][sl + 2] = qa.z * iv.z;
        aQ[cl][sl + 3] = qa.w * iv.w;
      }
#pragma unroll
      for (int v = 0; v < 4; ++v) {
        int f = t + v * 256;
        int cl = f >> 5;
        int sl = (f & 31) << 2;
        float4 ka = *(const float4*)(kbase + (size_t)(c0 + cl) * SS + j0 + sl);
        float4 ik = *(const float4*)(ivk + j0 + sl);
        bK[cl][sl + 0] = ka.x * ik.x;
        bK[cl][sl + 1] = ka.y * ik.y;
        bK[cl][sl + 2] = ka.z * ik.z;
        bK[cl][sl + 3] = ka.w * ik.w;
      }
      __syncthreads();
#pragma unroll
      for (int kc = 0; kc < KC; ++kc) {
        float4 a0 = *(const float4*)&aQ[kc][ti * 4];
        float4 b0 = *(const float4*)&bK[kc][tj * 8];
        float4 b1 = *(const float4*)&bK[kc][tj * 8 + 4];
        float av[4] = {a0.x, a0.y, a0.z, a0.w};
        float bv[8] = {b0.x, b0.y, b0.z, b0.w, b1.x, b1.y, b1.z, b1.w};
#pragma unroll
        for (int r = 0; r < 4; ++r)
#pragma unroll
          for (int rr = 0; rr < 8; ++rr)
            acc[r][rr] = fmaf(av[r], bv[rr], acc[r][rr]);
      }
    }
    __syncthreads();
#pragma unroll
    for (int r = 0; r < 4; ++r) {
      float v = acc[r][0];
      int jb = j0 + tj * 8;
#pragma unroll
      for (int rr = 1; rr < 8; ++rr) {
        if (acc[r][rr] > v) { v = acc[r][rr]; jb = j0 + tj * 8 + rr; }
      }
      redv[ti * 4 + r][tj] = v;
      redj[ti * 4 + r][tj] = jb;
    }
    __syncthreads();
    if (t < TI) {
#pragma unroll
      for (int ww = 0; ww < 16; ++ww) {
        float v = redv[t][ww];
        if (v > best_v) { best_v = v; best_j = redj[t][ww]; }
      }
    }
  }
  if (t < TI) amax[b * SS + i0 + t] = best_j;
}

__global__ __launch_bounds__(256) void loss_kernel(
    const float* __restrict__ qg, const float* __restrict__ kg,
    const float* __restrict__ invq, const float* __restrict__ invk,
    const int* __restrict__ amax, const int* __restrict__ negidx,
    float* __restrict__ out) {
  int t = blockIdx.x * 256 + threadIdx.x;
  int b = t >> 10;
  int s = t & (SS - 1);
  int js = amax[t];
  int nb = negidx[b];
  const float* qcol = qg + (size_t)b * CC * SS + s;
  const float* kpcol = kg + (size_t)b * CC * SS + js;
  const float* kncol = kg + (size_t)nb * CC * SS + s;
  float dp = 0.f, dn = 0.f;
#pragma unroll 8
  for (int c = 0; c < CC; ++c) {
    float q = qcol[(size_t)c * SS];
    dp = fmaf(q, kpcol[(size_t)c * SS], dp);
    dn = fmaf(q, kncol[(size_t)c * SS], dn);
  }
  float iq = invq[t];
  float pv = dp * iq * invk[b * SS + js] * 10.0f;
  float nv = dn * iq * invk[nb * SS + s] * 10.0f;
  float elem = logf(expf(pv) + expf(nv) + 1e-6f) - pv;

  __shared__ float red[256];
  red[threadIdx.x] = elem;
  __syncthreads();
  for (int o = 128; o > 0; o >>= 1) {
    if (threadIdx.x < o) red[threadIdx.x] += red[threadIdx.x + o];
    __syncthreads();
  }
  if (threadIdx.x == 0) atomicAdd(out, red[0] * (1.0f / (BB * SS)));
}

// ---------------------------------------------------------------------------
extern "C" void kernel_launch(void* const* d_in, const int* in_sizes, int n_in,
                              void* d_out, int out_size, void* d_ws, size_t ws_size,
                              hipStream_t stream) {
  const float* qb = (const float*)d_in[0];
  const float* kb = (const float*)d_in[1];
  const float* qg = (const float*)d_in[2];
  const float* kg = (const float*)d_in[3];
  const int* labels = (const int*)d_in[4];

  char* ws = (char*)d_ws;
  // fast-path layout (33 MB total, proven available):
  float* invqb = (float*)ws;                                   // 128 KB (unused)
  float* invkb = (float*)(ws + 128 * 1024);                    // 128 KB
  float* invkg = (float*)(ws + 256 * 1024);                    // 128 KB
  unsigned long long* best = (unsigned long long*)(ws + 384 * 1024);  // 256 KB
  int* negidx = (int*)(ws + 640 * 1024);                       // small
  unsigned short* qt = (unsigned short*)(ws + (1 << 20));      // 16 MB
  unsigned short* kt = (unsigned short*)(ws + (17 << 20));     // 16 MB
  unsigned short* kgt = qt;  // aliases qt — written after simargmax (stream-serial)

  const size_t need = (size_t)33 * 1024 * 1024;
  const bool fast = ws_size >= need;

  hipMemsetAsync(d_out, 0, sizeof(float), stream);

  if (fast) {
    hipMemsetAsync(best, 0, BB * SS * sizeof(unsigned long long), stream);
    negidx_kernel<<<1, 512, 0, stream>>>(labels, negidx);
    transnorm_kernel<<<2048, 256, 0, stream>>>(qb, kb, qt, kt, invqb, invkb);
    simargmax_mfma<<<2048, 256, 0, stream>>>(qt, kt, invkb, best);
    transnorm_kernel<<<1024, 256, 0, stream>>>(kg, kg, kgt, kgt, invkg, invkg);
    loss_fused_kernel<<<1024, 256, 0, stream>>>(qg, kgt, invkg, best, negidx,
                                                (float*)d_out);
  } else {
    float* inv = (float*)ws;
    int* amax = (int*)(ws + 512 * 1024);
    int* negidx2 = (int*)(ws + 640 * 1024);
    norms_kernel<<<(4 * BB * SS) / 256, 256, 0, stream>>>(qb, kb, qg, kg, inv);
    simargmax_kernel<<<BB * (SS / TI), 256, 0, stream>>>(
        qb, kb, inv + 0 * BB * SS, inv + 1 * BB * SS, amax);
    negidx_kernel<<<1, 512, 0, stream>>>(labels, negidx2);
    loss_kernel<<<(BB * SS) / 256, 256, 0, stream>>>(
        qg, kg, inv + 2 * BB * SS, inv + 3 * BB * SS, amax, negidx2,
        (float*)d_out);
  }
}